// Round 4
// baseline (110.304 us; speedup 1.0000x reference)
//
#include <hip/hip_runtime.h>

#define NSCENE 64
#define NPTS   16384
#define SIN    256
#define SH     128
#define SOUT   128

// ---- workspace layout (bytes) ----
#define WS_PARTIAL 0              // 64*64 int (per-block partial histograms)
#define WS_OFFSETS 16384          // 65 int
#define WS_PERM    17408          // 16384 int
#define WS_WBF16   82944          // 5,242,880 shorts = 10,485,760 B
#define W0_ELEMS   (NSCENE*SH*SIN)    // 2,097,152
#define W1_ELEMS   (NSCENE*SOUT*SH)   // 1,048,576
#define W2_ELEMS   (NSCENE*SOUT*SIN)  // 2,097,152
#define WTOT       (W0_ELEMS+W1_ELEMS+W2_ELEMS)  // 5,242,880
#define CONV_BLOCKS (WTOT/2048)   // 2560 blocks x 256 thr x 8 elems

typedef __attribute__((ext_vector_type(8))) short bf16x8;
typedef __attribute__((ext_vector_type(4))) float f32x4;

__device__ __forceinline__ short f2bf(float f) {
  unsigned int u = __float_as_uint(f);
  unsigned int r = (u + 0x7FFFu + ((u >> 16) & 1u)) >> 16;
  return (short)(r & 0xFFFFu);
}

// ---------------- K1: partial histograms + weight bf16 conversion (R2-proven) ----------------

__global__ __launch_bounds__(256) void prep_kernel(
    const int* __restrict__ bidx,
    const float* __restrict__ kls0, const float* __restrict__ kls1,
    const float* __restrict__ kls2,
    int* __restrict__ partial, short* __restrict__ wb)
{
  int b = blockIdx.x;
  int tid = threadIdx.x;
  if (b < 64) {
    __shared__ int lh[NSCENE];
    if (tid < NSCENE) lh[tid] = 0;
    __syncthreads();
    atomicAdd(&lh[bidx[b * 256 + tid]], 1);
    __syncthreads();
    if (tid < NSCENE) partial[b * 64 + tid] = lh[tid];
  } else {
    int e = ((b - 64) * 256 + tid) * 8;
    if (e < WTOT) {
      const float* src;
      if (e < W0_ELEMS) src = kls0 + e;
      else if (e < W0_ELEMS + W1_ELEMS) src = kls1 + (e - W0_ELEMS);
      else src = kls2 + (e - W0_ELEMS - W1_ELEMS);
      float4 u0 = *reinterpret_cast<const float4*>(src);
      float4 u1 = *reinterpret_cast<const float4*>(src + 4);
      bf16x8 v = (bf16x8){f2bf(u0.x), f2bf(u0.y), f2bf(u0.z), f2bf(u0.w),
                          f2bf(u1.x), f2bf(u1.y), f2bf(u1.z), f2bf(u1.w)};
      *reinterpret_cast<bf16x8*>(wb + e) = v;
    }
  }
}

// ---------------- K2: scan + scatter (R2-proven) ----------------

__global__ __launch_bounds__(256) void scatter_kernel(
    const int* __restrict__ bidx, const int* __restrict__ partial,
    int* __restrict__ offsets, int* __restrict__ perm)
{
  __shared__ int cur[NSCENE];
  int b = blockIdx.x;
  int tid = threadIdx.x;
  if (tid < 64) {
    int s = tid;
    int colpre = 0, total = 0;
    for (int bb = 0; bb < 64; ++bb) {
      int v = partial[bb * 64 + s];
      if (bb < b) colpre += v;
      total += v;
    }
    int v = total;
    for (int off = 1; off < 64; off <<= 1) {
      int t = __shfl_up(v, off);
      if (s >= off) v += t;
    }
    int sceneoff = v - total;
    cur[s] = sceneoff + colpre;
    if (b == 0) {
      offsets[s] = sceneoff;
      if (s == 63) offsets[64] = NPTS;
    }
  }
  __syncthreads();
  int n = b * 256 + tid;
  int s = bidx[n];
  int pos = atomicAdd(&cur[s], 1);
  perm[pos] = n;
}

// ---------------- K3: fused, barrier-free, wave-independent ----------------
// grid 512: bid = b8*64 + s  (scene pinned to XCD bid%8 == s%8).
// 256 threads = 4 waves; each wave owns a 16-point x 128-col tile.

template<bool BF16W>
__device__ __forceinline__ bf16x8 ldw(const short* bptr, const float* fptr) {
  if constexpr (BF16W) {
    return *reinterpret_cast<const bf16x8*>(bptr);
  } else {
    float4 u0 = *reinterpret_cast<const float4*>(fptr);
    float4 u1 = *reinterpret_cast<const float4*>(fptr + 4);
    return (bf16x8){f2bf(u0.x), f2bf(u0.y), f2bf(u0.z), f2bf(u0.w),
                    f2bf(u1.x), f2bf(u1.y), f2bf(u1.z), f2bf(u1.w)};
  }
}

template<bool BF16W>
__global__ __launch_bounds__(256) void fused_kernel(
    const float* __restrict__ kls0, const float* __restrict__ kls1,
    const float* __restrict__ kls2, const float* __restrict__ bias0,
    const float* __restrict__ bias1, const float* __restrict__ x,
    const int* __restrict__ offsets, const int* __restrict__ perm,
    const short* __restrict__ wb, float* __restrict__ out)
{
  __shared__ __align__(16) short snet[4][16][SH + 8];  // wave-private slices

  const int s    = blockIdx.x & 63;
  const int b8   = blockIdx.x >> 6;     // 0..7
  const int base = offsets[s];
  const int cnt  = offsets[s + 1] - base;
  const int tid  = threadIdx.x;
  const int lane = tid & 63;
  const int w    = tid >> 6;            // 0..3
  const int l15  = lane & 15;
  const int lh4  = lane >> 4;

  const float* W0 = kls0 + (size_t)s * SH * SIN;
  const float* W1 = kls1 + (size_t)s * SOUT * SH;
  const float* W2 = kls2 + (size_t)s * SOUT * SIN;
  const short* B0 = wb + (size_t)s * SH * SIN;
  const short* B1 = wb + W0_ELEMS + (size_t)s * SOUT * SH;
  const short* B2 = wb + W0_ELEMS + W1_ELEMS + (size_t)s * SOUT * SIN;

  float bv0[8], bv1[8];
#pragma unroll
  for (int nt = 0; nt < 8; ++nt) {
    bv0[nt] = bias0[(size_t)s * SH + nt * 16 + l15];
    bv1[nt] = bias1[(size_t)s * SOUT + nt * 16 + l15];
  }

  short (*sn)[SH + 8] = snet[w];

  for (int t = b8 * 4 + w; t * 16 < cnt; t += 32) {
    int pr = t * 16 + l15;
    int np = (pr < cnt) ? perm[base + pr] : -1;
    const float* px = x + (size_t)(np < 0 ? 0 : np) * SIN;

    f32x4 acc0[8], acc2[8];
#pragma unroll
    for (int nt = 0; nt < 8; ++nt) {
      acc0[nt] = (f32x4){bv0[nt], bv0[nt], bv0[nt], bv0[nt]};
      acc2[nt] = (f32x4){bv1[nt], bv1[nt], bv1[nt], bv1[nt]};
    }

    // ---- layers 0 + 2 interleaved; A-frags straight from global x ----
#pragma unroll
    for (int ks = 0; ks < 8; ++ks) {
      const int kc = ks * 32 + lh4 * 8;
      float4 u0 = *reinterpret_cast<const float4*>(px + kc);
      float4 u1 = *reinterpret_cast<const float4*>(px + kc + 4);
      bf16x8 aP = (bf16x8){f2bf(u0.x), f2bf(u0.y), f2bf(u0.z), f2bf(u0.w),
                           f2bf(u1.x), f2bf(u1.y), f2bf(u1.z), f2bf(u1.w)};
      bf16x8 aR = (bf16x8){f2bf(fmaxf(u0.x, 0.f)), f2bf(fmaxf(u0.y, 0.f)),
                           f2bf(fmaxf(u0.z, 0.f)), f2bf(fmaxf(u0.w, 0.f)),
                           f2bf(fmaxf(u1.x, 0.f)), f2bf(fmaxf(u1.y, 0.f)),
                           f2bf(fmaxf(u1.z, 0.f)), f2bf(fmaxf(u1.w, 0.f))};
#pragma unroll
      for (int nt = 0; nt < 8; ++nt) {
        const size_t wro = (size_t)(nt * 16 + l15) * SIN + kc;
        bf16x8 b0f = ldw<BF16W>(B0 + wro, W0 + wro);
        bf16x8 b2f = ldw<BF16W>(B2 + wro, W2 + wro);
        acc0[nt] = __builtin_amdgcn_mfma_f32_16x16x32_bf16(aR, b0f, acc0[nt], 0, 0, 0);
        acc2[nt] = __builtin_amdgcn_mfma_f32_16x16x32_bf16(aP, b2f, acc2[nt], 0, 0, 0);
      }
    }

    // ---- relu(net) -> wave-private LDS (transpose for layer-1 A) ----
#pragma unroll
    for (int nt = 0; nt < 8; ++nt)
#pragma unroll
      for (int r4 = 0; r4 < 4; ++r4)
        sn[lh4 * 4 + r4][nt * 16 + l15] = f2bf(fmaxf(acc0[nt][r4], 0.f));

    // ---- layer 1 ----
#pragma unroll
    for (int ks = 0; ks < 4; ++ks) {
      const int kc = ks * 32 + lh4 * 8;
      bf16x8 aS = *reinterpret_cast<const bf16x8*>(&sn[l15][kc]);
#pragma unroll
      for (int nt = 0; nt < 8; ++nt) {
        const size_t wro = (size_t)(nt * 16 + l15) * SH + kc;
        bf16x8 b1f = ldw<BF16W>(B1 + wro, W1 + wro);
        acc2[nt] = __builtin_amdgcn_mfma_f32_16x16x32_bf16(aS, b1f, acc2[nt], 0, 0, 0);
      }
    }

    // ---- store ----
#pragma unroll
    for (int r4 = 0; r4 < 4; ++r4) {
      int pt = __shfl(np, lh4 * 4 + r4);
      if (pt >= 0) {
#pragma unroll
        for (int nt = 0; nt < 8; ++nt)
          out[(size_t)pt * SOUT + nt * 16 + l15] = acc2[nt][r4];
      }
    }
  }
}

// ---------------- launch ----------------

extern "C" void kernel_launch(void* const* d_in, const int* in_sizes, int n_in,
                              void* d_out, int out_size, void* d_ws, size_t ws_size,
                              hipStream_t stream) {
  const float* kls0  = (const float*)d_in[0];
  const float* kls1  = (const float*)d_in[1];
  const float* kls2  = (const float*)d_in[2];
  const float* bias0 = (const float*)d_in[3];
  const float* bias1 = (const float*)d_in[4];
  const float* x     = (const float*)d_in[5];
  const int*   bidx  = (const int*)d_in[6];
  float* out = (float*)d_out;

  int*   partial = (int*)((char*)d_ws + WS_PARTIAL);
  int*   offsets = (int*)((char*)d_ws + WS_OFFSETS);
  int*   perm    = (int*)((char*)d_ws + WS_PERM);
  short* wb      = (short*)((char*)d_ws + WS_WBF16);

  bool bf16w = ws_size >= (size_t)WS_WBF16 + sizeof(short) * (size_t)WTOT;

  prep_kernel<<<bf16w ? (64 + CONV_BLOCKS) : 64, 256, 0, stream>>>(
      bidx, kls0, kls1, kls2, partial, wb);
  scatter_kernel<<<64, 256, 0, stream>>>(bidx, partial, offsets, perm);
  if (bf16w)
    fused_kernel<true><<<512, 256, 0, stream>>>(kls0, kls1, kls2, bias0, bias1,
                                                x, offsets, perm, wb, out);
  else
    fused_kernel<false><<<512, 256, 0, stream>>>(kls0, kls1, kls2, bias0, bias1,
                                                 x, offsets, perm, wb, out);
}

// Round 5
// 32.865 us; speedup vs baseline: 3.3562x; 3.3562x over previous
//
#include <hip/hip_runtime.h>

#define NSCENE 64
#define NPTS   16384
#define SIN    256
#define SH     128
#define SOUT   128
#define TILE_P 32

// ---- workspace layout (bytes) ----
#define WS_PARTIAL 0              // 64*64 int (per-block partial histograms)
#define WS_OFFSETS 16384          // 65 int
#define WS_PERM    17408          // 16384 int
#define WS_WBF16   82944          // 5,242,880 shorts = 10,485,760 B
#define W0_ELEMS   (NSCENE*SH*SIN)    // 2,097,152
#define W1_ELEMS   (NSCENE*SOUT*SH)   // 1,048,576
#define W2_ELEMS   (NSCENE*SOUT*SIN)  // 2,097,152
#define WTOT       (W0_ELEMS+W1_ELEMS+W2_ELEMS)  // 5,242,880
#define CONV_BLOCKS (WTOT/2048)   // 2560 blocks x 256 thr x 8 elems

typedef __attribute__((ext_vector_type(8))) short bf16x8;
typedef __attribute__((ext_vector_type(4))) float f32x4;

__device__ __forceinline__ short f2bf(float f) {
  unsigned int u = __float_as_uint(f);
  unsigned int r = (u + 0x7FFFu + ((u >> 16) & 1u)) >> 16;
  return (short)(r & 0xFFFFu);
}

// ---------------- K1: partial histograms + weight bf16 conversion (R2-proven) ----------------

__global__ __launch_bounds__(256) void prep_kernel(
    const int* __restrict__ bidx,
    const float* __restrict__ kls0, const float* __restrict__ kls1,
    const float* __restrict__ kls2,
    int* __restrict__ partial, short* __restrict__ wb)
{
  int b = blockIdx.x;
  int tid = threadIdx.x;
  if (b < 64) {
    __shared__ int lh[NSCENE];
    if (tid < NSCENE) lh[tid] = 0;
    __syncthreads();
    atomicAdd(&lh[bidx[b * 256 + tid]], 1);
    __syncthreads();
    if (tid < NSCENE) partial[b * 64 + tid] = lh[tid];
  } else {
    int e = ((b - 64) * 256 + tid) * 8;
    if (e < WTOT) {
      const float* src;
      if (e < W0_ELEMS) src = kls0 + e;
      else if (e < W0_ELEMS + W1_ELEMS) src = kls1 + (e - W0_ELEMS);
      else src = kls2 + (e - W0_ELEMS - W1_ELEMS);
      float4 u0 = *reinterpret_cast<const float4*>(src);
      float4 u1 = *reinterpret_cast<const float4*>(src + 4);
      bf16x8 v = (bf16x8){f2bf(u0.x), f2bf(u0.y), f2bf(u0.z), f2bf(u0.w),
                          f2bf(u1.x), f2bf(u1.y), f2bf(u1.z), f2bf(u1.w)};
      *reinterpret_cast<bf16x8*>(wb + e) = v;
    }
  }
}

// ---------------- K2: scan + scatter (R2-proven) ----------------

__global__ __launch_bounds__(256) void scatter_kernel(
    const int* __restrict__ bidx, const int* __restrict__ partial,
    int* __restrict__ offsets, int* __restrict__ perm)
{
  __shared__ int cur[NSCENE];
  int b = blockIdx.x;
  int tid = threadIdx.x;
  if (tid < 64) {
    int s = tid;
    int colpre = 0, total = 0;
    for (int bb = 0; bb < 64; ++bb) {
      int v = partial[bb * 64 + s];
      if (bb < b) colpre += v;
      total += v;
    }
    int v = total;
    for (int off = 1; off < 64; off <<= 1) {
      int t = __shfl_up(v, off);
      if (s >= off) v += t;
    }
    int sceneoff = v - total;
    cur[s] = sceneoff + colpre;
    if (b == 0) {
      offsets[s] = sceneoff;
      if (s == 63) offsets[64] = NPTS;
    }
  }
  __syncthreads();
  int n = b * 256 + tid;
  int s = bidx[n];
  int pos = atomicAdd(&cur[s], 1);
  perm[pos] = n;
}

// ---------------- K3: fused per-scene GEMM ----------------
// grid 512: bid = t0*64 + s (scene pinned to XCD bid%8 == s%8).
// 512 threads = 8 waves; wave w owns output cols [w*16, w*16+16),
// tile = 32 points (mt=2). W1 fragments cached in registers across tiles.

template<bool BF16W>
__global__ __launch_bounds__(512) void fused_kernel(
    const float* __restrict__ kls0, const float* __restrict__ kls1,
    const float* __restrict__ kls2, const float* __restrict__ bias0,
    const float* __restrict__ bias1, const float* __restrict__ x,
    const int* __restrict__ offsets, const int* __restrict__ perm,
    const short* __restrict__ wb, float* __restrict__ out)
{
  __shared__ __align__(16) short xr[TILE_P][SIN + 8];   // relu(x) bf16
  __shared__ __align__(16) short xp[TILE_P][SIN + 8];   // x bf16
  __shared__ __align__(16) short snet[TILE_P][SH + 8];  // relu(net) bf16
  __shared__ int ptile[TILE_P];

  const int s    = blockIdx.x & 63;
  const int t0   = blockIdx.x >> 6;
  const int base = offsets[s];
  const int cnt  = offsets[s + 1] - base;
  const int tid  = threadIdx.x;
  const int lane = tid & 63;
  const int w    = tid >> 6;            // 0..7
  const int l15  = lane & 15;
  const int lh4  = lane >> 4;
  const int col  = w * 16 + l15;        // output / weight row this lane owns

  const float* W0 = kls0 + (size_t)s * SH * SIN;
  const float* W1 = kls1 + (size_t)s * SOUT * SH;
  const float* W2 = kls2 + (size_t)s * SOUT * SIN;
  const short* B0 = wb + (size_t)s * SH * SIN + (size_t)col * SIN;
  const short* B1 = wb + W0_ELEMS + (size_t)s * SOUT * SH + (size_t)col * SH;
  const short* B2 = wb + W0_ELEMS + W1_ELEMS + (size_t)s * SOUT * SIN + (size_t)col * SIN;

  const float bv0 = bias0[(size_t)s * SH + col];
  const float bv1 = bias1[(size_t)s * SOUT + col];

  // ---- W1 fragments are tile-invariant: load once (16 VGPRs) ----
  bf16x8 b1c[4];
#pragma unroll
  for (int ks = 0; ks < 4; ++ks) {
    int kc = ks * 32 + lh4 * 8;
    if constexpr (BF16W) {
      b1c[ks] = *reinterpret_cast<const bf16x8*>(B1 + kc);
    } else {
      const float* w1r = W1 + (size_t)col * SH + kc;
      float4 u0 = *reinterpret_cast<const float4*>(w1r);
      float4 u1 = *reinterpret_cast<const float4*>(w1r + 4);
      b1c[ks] = (bf16x8){f2bf(u0.x), f2bf(u0.y), f2bf(u0.z), f2bf(u0.w),
                         f2bf(u1.x), f2bf(u1.y), f2bf(u1.z), f2bf(u1.w)};
    }
  }

  for (int t = t0; t * TILE_P < cnt; t += 8) {
    __syncthreads();  // protect LDS reuse across tile iterations

    // ---- stage x tile: 16 threads per row, 16 floats each ----
    {
      int r  = tid >> 4;
      int cg = tid & 15;
      int prow = t * TILE_P + r;
      int np = (prow < cnt) ? perm[base + prow] : -1;
      if (cg == 0) ptile[r] = np;
      const float* xrow = x + (size_t)(np < 0 ? 0 : np) * SIN;
      int c0 = cg * 16;
      for (int j = 0; j < 16; j += 4) {
        float4 v = make_float4(0.f, 0.f, 0.f, 0.f);
        if (np >= 0) v = *reinterpret_cast<const float4*>(xrow + c0 + j);
        short4 p, q;
        p.x = f2bf(v.x); p.y = f2bf(v.y); p.z = f2bf(v.z); p.w = f2bf(v.w);
        q.x = f2bf(fmaxf(v.x, 0.f)); q.y = f2bf(fmaxf(v.y, 0.f));
        q.z = f2bf(fmaxf(v.z, 0.f)); q.w = f2bf(fmaxf(v.w, 0.f));
        *reinterpret_cast<short4*>(&xp[r][c0 + j]) = p;
        *reinterpret_cast<short4*>(&xr[r][c0 + j]) = q;
      }
    }
    __syncthreads();

    // ---- layers 0 + 2 interleaved (independent load streams) ----
    f32x4 acc0[2], acc[2];
#pragma unroll
    for (int mt = 0; mt < 2; ++mt) {
      acc0[mt] = (f32x4){bv0, bv0, bv0, bv0};
      acc[mt]  = (f32x4){bv1, bv1, bv1, bv1};
    }
#pragma unroll
    for (int ks = 0; ks < 8; ++ks) {
      int kc = ks * 32 + lh4 * 8;
      bf16x8 b0f, b2f;
      if constexpr (BF16W) {
        b0f = *reinterpret_cast<const bf16x8*>(B0 + kc);
        b2f = *reinterpret_cast<const bf16x8*>(B2 + kc);
      } else {
        const float* w0r = W0 + (size_t)col * SIN + kc;
        const float* w2r = W2 + (size_t)col * SIN + kc;
        float4 u0 = *reinterpret_cast<const float4*>(w0r);
        float4 u1 = *reinterpret_cast<const float4*>(w0r + 4);
        float4 v0 = *reinterpret_cast<const float4*>(w2r);
        float4 v1 = *reinterpret_cast<const float4*>(w2r + 4);
        b0f = (bf16x8){f2bf(u0.x), f2bf(u0.y), f2bf(u0.z), f2bf(u0.w),
                       f2bf(u1.x), f2bf(u1.y), f2bf(u1.z), f2bf(u1.w)};
        b2f = (bf16x8){f2bf(v0.x), f2bf(v0.y), f2bf(v0.z), f2bf(v0.w),
                       f2bf(v1.x), f2bf(v1.y), f2bf(v1.z), f2bf(v1.w)};
      }
#pragma unroll
      for (int mt = 0; mt < 2; ++mt) {
        bf16x8 aR = *reinterpret_cast<const bf16x8*>(&xr[mt * 16 + l15][kc]);
        bf16x8 aP = *reinterpret_cast<const bf16x8*>(&xp[mt * 16 + l15][kc]);
        acc0[mt] = __builtin_amdgcn_mfma_f32_16x16x32_bf16(aR, b0f, acc0[mt], 0, 0, 0);
        acc[mt]  = __builtin_amdgcn_mfma_f32_16x16x32_bf16(aP, b2f, acc[mt],  0, 0, 0);
      }
    }

    // write relu(net) -> LDS (D layout: row=(lane>>4)*4+reg, col=lane&15)
#pragma unroll
    for (int mt = 0; mt < 2; ++mt)
#pragma unroll
      for (int r4 = 0; r4 < 4; ++r4)
        snet[mt * 16 + lh4 * 4 + r4][col] = f2bf(fmaxf(acc0[mt][r4], 0.f));
    __syncthreads();  // snet ready

    // ---- layer 1: acc += relu(net) @ W1^T (weights already in registers) ----
#pragma unroll
    for (int ks = 0; ks < 4; ++ks) {
      int kc = ks * 32 + lh4 * 8;
#pragma unroll
      for (int mt = 0; mt < 2; ++mt) {
        bf16x8 aS = *reinterpret_cast<const bf16x8*>(&snet[mt * 16 + l15][kc]);
        acc[mt] = __builtin_amdgcn_mfma_f32_16x16x32_bf16(aS, b1c[ks], acc[mt], 0, 0, 0);
      }
    }

    // ---- store ----
#pragma unroll
    for (int mt = 0; mt < 2; ++mt)
#pragma unroll
      for (int r4 = 0; r4 < 4; ++r4) {
        int row = mt * 16 + lh4 * 4 + r4;
        int pt = ptile[row];
        if (pt >= 0) out[(size_t)pt * SOUT + col] = acc[mt][r4];
      }
  }
}

// ---------------- launch ----------------

extern "C" void kernel_launch(void* const* d_in, const int* in_sizes, int n_in,
                              void* d_out, int out_size, void* d_ws, size_t ws_size,
                              hipStream_t stream) {
  const float* kls0  = (const float*)d_in[0];
  const float* kls1  = (const float*)d_in[1];
  const float* kls2  = (const float*)d_in[2];
  const float* bias0 = (const float*)d_in[3];
  const float* bias1 = (const float*)d_in[4];
  const float* x     = (const float*)d_in[5];
  const int*   bidx  = (const int*)d_in[6];
  float* out = (float*)d_out;

  int*   partial = (int*)((char*)d_ws + WS_PARTIAL);
  int*   offsets = (int*)((char*)d_ws + WS_OFFSETS);
  int*   perm    = (int*)((char*)d_ws + WS_PERM);
  short* wb      = (short*)((char*)d_ws + WS_WBF16);

  bool bf16w = ws_size >= (size_t)WS_WBF16 + sizeof(short) * (size_t)WTOT;

  prep_kernel<<<bf16w ? (64 + CONV_BLOCKS) : 64, 256, 0, stream>>>(
      bidx, kls0, kls1, kls2, partial, wb);
  scatter_kernel<<<64, 256, 0, stream>>>(bidx, partial, offsets, perm);
  if (bf16w)
    fused_kernel<true><<<512, 512, 0, stream>>>(kls0, kls1, kls2, bias0, bias1,
                                                x, offsets, perm, wb, out);
  else
    fused_kernel<false><<<512, 512, 0, stream>>>(kls0, kls1, kls2, bias0, bias1,
                                                 x, offsets, perm, wb, out);
}

// Round 6
// 28.748 us; speedup vs baseline: 3.8369x; 1.1432x over previous
//
#include <hip/hip_runtime.h>

#define NSCENE 64
#define NPTS   16384
#define SIN    256
#define SH     128
#define SOUT   128
#define TILE_P 32

// ---- workspace layout (bytes) ----
#define WS_PARTIAL 0              // 64*64 int (per-block partial histograms)
#define WS_OFFSETS 16384          // 65 int
#define WS_PERM    17408          // 16384 int
#define WS_WBF16   82944          // 5,242,880 shorts = 10,485,760 B (fragment-ordered)
#define W0_ELEMS   (NSCENE*SH*SIN)    // 2,097,152 (32768/scene)
#define W1_ELEMS   (NSCENE*SOUT*SH)   // 1,048,576 (16384/scene)
#define W2_ELEMS   (NSCENE*SOUT*SIN)  // 2,097,152 (32768/scene)
#define WTOT       (W0_ELEMS+W1_ELEMS+W2_ELEMS)  // 5,242,880
#define CONV_BLOCKS (WTOT/2048)   // 2560 blocks x 256 thr x 8 elems
// fragment-order within a scene region: [w][ks][lane][8]  (elems)
//   L0: w<<12 | ks<<9 | lane<<3   (8 ks)   L1: w<<11 | ks<<9 | lane<<3 (4 ks)
// lane l supplies W[row = w*16 + (l&15)][k = ks*32 + (l>>4)*8 .. +8]

typedef __attribute__((ext_vector_type(8))) short bf16x8;
typedef __attribute__((ext_vector_type(4))) float f32x4;

__device__ __forceinline__ short f2bf(float f) {
  unsigned int u = __float_as_uint(f);
  unsigned int r = (u + 0x7FFFu + ((u >> 16) & 1u)) >> 16;
  return (short)(r & 0xFFFFu);
}

__device__ __forceinline__ bf16x8 cvt8(const float* src) {
  float4 u0 = *reinterpret_cast<const float4*>(src);
  float4 u1 = *reinterpret_cast<const float4*>(src + 4);
  return (bf16x8){f2bf(u0.x), f2bf(u0.y), f2bf(u0.z), f2bf(u0.w),
                  f2bf(u1.x), f2bf(u1.y), f2bf(u1.z), f2bf(u1.w)};
}

// ---------------- K1: partial histograms + fragment-ordered weight conversion ----------------

__global__ __launch_bounds__(256) void prep_kernel(
    const int* __restrict__ bidx,
    const float* __restrict__ kls0, const float* __restrict__ kls1,
    const float* __restrict__ kls2,
    int* __restrict__ partial, short* __restrict__ wb)
{
  int b = blockIdx.x;
  int tid = threadIdx.x;
  if (b < 64) {
    __shared__ int lh[NSCENE];
    if (tid < NSCENE) lh[tid] = 0;
    __syncthreads();
    atomicAdd(&lh[bidx[b * 256 + tid]], 1);
    __syncthreads();
    if (tid < NSCENE) partial[b * 64 + tid] = lh[tid];
  } else {
    int e = ((b - 64) * 256 + tid) * 8;   // output elem index (8 shorts/thread)
    if (e < WTOT) {
      const float* src;
      if (e < W0_ELEMS) {
        int s = e >> 15, r = e & 32767;
        int w = r >> 12, ks = (r >> 9) & 7, l = (r >> 3) & 63;
        int row = w * 16 + (l & 15), k = ks * 32 + (l >> 4) * 8;
        src = kls0 + ((size_t)s << 15) + row * SIN + k;
      } else if (e < W0_ELEMS + W1_ELEMS) {
        int e1 = e - W0_ELEMS;
        int s = e1 >> 14, r = e1 & 16383;
        int w = r >> 11, ks = (r >> 9) & 3, l = (r >> 3) & 63;
        int row = w * 16 + (l & 15), k = ks * 32 + (l >> 4) * 8;
        src = kls1 + ((size_t)s << 14) + row * SH + k;
      } else {
        int e2 = e - W0_ELEMS - W1_ELEMS;
        int s = e2 >> 15, r = e2 & 32767;
        int w = r >> 12, ks = (r >> 9) & 7, l = (r >> 3) & 63;
        int row = w * 16 + (l & 15), k = ks * 32 + (l >> 4) * 8;
        src = kls2 + ((size_t)s << 15) + row * SIN + k;
      }
      *reinterpret_cast<bf16x8*>(wb + e) = cvt8(src);   // coalesced write
    }
  }
}

// ---------------- K2: scan + scatter (R2-proven) ----------------

__global__ __launch_bounds__(256) void scatter_kernel(
    const int* __restrict__ bidx, const int* __restrict__ partial,
    int* __restrict__ offsets, int* __restrict__ perm)
{
  __shared__ int cur[NSCENE];
  int b = blockIdx.x;
  int tid = threadIdx.x;
  if (tid < 64) {
    int s = tid;
    int colpre = 0, total = 0;
    for (int bb = 0; bb < 64; ++bb) {
      int v = partial[bb * 64 + s];
      if (bb < b) colpre += v;
      total += v;
    }
    int v = total;
    for (int off = 1; off < 64; off <<= 1) {
      int t = __shfl_up(v, off);
      if (s >= off) v += t;
    }
    int sceneoff = v - total;
    cur[s] = sceneoff + colpre;
    if (b == 0) {
      offsets[s] = sceneoff;
      if (s == 63) offsets[64] = NPTS;
    }
  }
  __syncthreads();
  int n = b * 256 + tid;
  int s = bidx[n];
  int pos = atomicAdd(&cur[s], 1);
  perm[pos] = n;
}

// ---------------- K3: fused per-scene GEMM (R5 structure, coalesced frag loads) ----------------
// grid 512: bid = t0*64 + s (scene pinned to XCD bid%8 == s%8).
// 512 threads = 8 waves; wave w owns output cols [w*16, w*16+16), tile = 32 points.

__global__ __launch_bounds__(512) void fused_kernel(
    const float* __restrict__ bias0, const float* __restrict__ bias1,
    const float* __restrict__ x,
    const int* __restrict__ offsets, const int* __restrict__ perm,
    const short* __restrict__ wb, float* __restrict__ out)
{
  __shared__ __align__(16) short xr[TILE_P][SIN + 8];   // relu(x) bf16
  __shared__ __align__(16) short xp[TILE_P][SIN + 8];   // x bf16
  __shared__ __align__(16) short snet[TILE_P][SH + 8];  // relu(net) bf16
  __shared__ int ptile[TILE_P];

  const int s    = blockIdx.x & 63;
  const int t0   = blockIdx.x >> 6;
  const int base = offsets[s];
  const int cnt  = offsets[s + 1] - base;
  const int tid  = threadIdx.x;
  const int lane = tid & 63;
  const int w    = tid >> 6;            // 0..7
  const int l15  = lane & 15;
  const int lh4  = lane >> 4;
  const int col  = w * 16 + l15;

  // fragment-ordered weight bases (coalesced: lane*16B within each 1KB frag)
  const short* B0s = wb + ((size_t)s << 15) + (w << 12) + (lane << 3);
  const short* B1s = wb + W0_ELEMS + ((size_t)s << 14) + (w << 11) + (lane << 3);
  const short* B2s = wb + W0_ELEMS + W1_ELEMS + ((size_t)s << 15) + (w << 12) + (lane << 3);

  const float bv0 = bias0[(size_t)s * SH + col];
  const float bv1 = bias1[(size_t)s * SOUT + col];

  // ---- W1 fragments are tile-invariant: load once (16 VGPRs) ----
  bf16x8 b1c[4];
#pragma unroll
  for (int ks = 0; ks < 4; ++ks)
    b1c[ks] = *reinterpret_cast<const bf16x8*>(B1s + (ks << 9));

  for (int t = t0; t * TILE_P < cnt; t += 8) {
    __syncthreads();  // protect LDS reuse across tile iterations

    // ---- stage x tile: 16 threads per row, 16 floats each ----
    {
      int r  = tid >> 4;
      int cg = tid & 15;
      int prow = t * TILE_P + r;
      int np = (prow < cnt) ? perm[base + prow] : -1;
      if (cg == 0) ptile[r] = np;
      const float* xrow = x + (size_t)(np < 0 ? 0 : np) * SIN;
      int c0 = cg * 16;
      for (int j = 0; j < 16; j += 4) {
        float4 v = make_float4(0.f, 0.f, 0.f, 0.f);
        if (np >= 0) v = *reinterpret_cast<const float4*>(xrow + c0 + j);
        short4 p, q;
        p.x = f2bf(v.x); p.y = f2bf(v.y); p.z = f2bf(v.z); p.w = f2bf(v.w);
        q.x = f2bf(fmaxf(v.x, 0.f)); q.y = f2bf(fmaxf(v.y, 0.f));
        q.z = f2bf(fmaxf(v.z, 0.f)); q.w = f2bf(fmaxf(v.w, 0.f));
        *reinterpret_cast<short4*>(&xp[r][c0 + j]) = p;
        *reinterpret_cast<short4*>(&xr[r][c0 + j]) = q;
      }
    }
    __syncthreads();

    // ---- layers 0 + 2 interleaved ----
    f32x4 acc0[2], acc[2];
#pragma unroll
    for (int mt = 0; mt < 2; ++mt) {
      acc0[mt] = (f32x4){bv0, bv0, bv0, bv0};
      acc[mt]  = (f32x4){bv1, bv1, bv1, bv1};
    }
#pragma unroll
    for (int ks = 0; ks < 8; ++ks) {
      int kc = ks * 32 + lh4 * 8;
      bf16x8 b0f = *reinterpret_cast<const bf16x8*>(B0s + (ks << 9));
      bf16x8 b2f = *reinterpret_cast<const bf16x8*>(B2s + (ks << 9));
#pragma unroll
      for (int mt = 0; mt < 2; ++mt) {
        bf16x8 aR = *reinterpret_cast<const bf16x8*>(&xr[mt * 16 + l15][kc]);
        bf16x8 aP = *reinterpret_cast<const bf16x8*>(&xp[mt * 16 + l15][kc]);
        acc0[mt] = __builtin_amdgcn_mfma_f32_16x16x32_bf16(aR, b0f, acc0[mt], 0, 0, 0);
        acc[mt]  = __builtin_amdgcn_mfma_f32_16x16x32_bf16(aP, b2f, acc[mt],  0, 0, 0);
      }
    }

    // write relu(net) -> LDS (D layout: row=(lane>>4)*4+reg, col=lane&15)
#pragma unroll
    for (int mt = 0; mt < 2; ++mt)
#pragma unroll
      for (int r4 = 0; r4 < 4; ++r4)
        snet[mt * 16 + lh4 * 4 + r4][col] = f2bf(fmaxf(acc0[mt][r4], 0.f));
    __syncthreads();  // snet ready

    // ---- layer 1: acc += relu(net) @ W1^T (weights in registers) ----
#pragma unroll
    for (int ks = 0; ks < 4; ++ks) {
      int kc = ks * 32 + lh4 * 8;
#pragma unroll
      for (int mt = 0; mt < 2; ++mt) {
        bf16x8 aS = *reinterpret_cast<const bf16x8*>(&snet[mt * 16 + l15][kc]);
        acc[mt] = __builtin_amdgcn_mfma_f32_16x16x32_bf16(aS, b1c[ks], acc[mt], 0, 0, 0);
      }
    }

    // ---- store ----
#pragma unroll
    for (int mt = 0; mt < 2; ++mt)
#pragma unroll
      for (int r4 = 0; r4 < 4; ++r4) {
        int row = mt * 16 + lh4 * 4 + r4;
        int pt = ptile[row];
        if (pt >= 0) out[(size_t)pt * SOUT + col] = acc[mt][r4];
      }
  }
}

// ---------------- launch ----------------

extern "C" void kernel_launch(void* const* d_in, const int* in_sizes, int n_in,
                              void* d_out, int out_size, void* d_ws, size_t ws_size,
                              hipStream_t stream) {
  const float* kls0  = (const float*)d_in[0];
  const float* kls1  = (const float*)d_in[1];
  const float* kls2  = (const float*)d_in[2];
  const float* bias0 = (const float*)d_in[3];
  const float* bias1 = (const float*)d_in[4];
  const float* x     = (const float*)d_in[5];
  const int*   bidx  = (const int*)d_in[6];
  float* out = (float*)d_out;

  int*   partial = (int*)((char*)d_ws + WS_PARTIAL);
  int*   offsets = (int*)((char*)d_ws + WS_OFFSETS);
  int*   perm    = (int*)((char*)d_ws + WS_PERM);
  short* wb      = (short*)((char*)d_ws + WS_WBF16);

  prep_kernel<<<64 + CONV_BLOCKS, 256, 0, stream>>>(
      bidx, kls0, kls1, kls2, partial, wb);
  scatter_kernel<<<64, 256, 0, stream>>>(bidx, partial, offsets, perm);
  fused_kernel<<<512, 512, 0, stream>>>(bias0, bias1, x, offsets, perm, wb, out);
}